// Round 4
// baseline (455.109 us; speedup 1.0000x reference)
//
#include <hip/hip_runtime.h>

#define KK 32
#define NODES 16384
#define NPB 64      // nodes per block
#define NPWV 16     // nodes per wave

typedef __bf16 bf16x8 __attribute__((ext_vector_type(8)));
typedef float  f32x4  __attribute__((ext_vector_type(4)));

union FragU { uint4 u; bf16x8 b; unsigned short s[8]; };

__device__ inline float bf2f(unsigned short v) {
    union { unsigned int u; float f; } t; t.u = ((unsigned int)v) << 16; return t.f;
}
__device__ inline unsigned short f2bf(float f) {
    union { float f; unsigned int u; } t; t.f = f;
    unsigned int u = t.u;
    return (unsigned short)((u + 0x7FFFu + ((u >> 16) & 1u)) >> 16);  // RNE
}
__device__ inline float silu_f(float x) { return x / (1.0f + __expf(-x)); }

__device__ inline float loadf(const void* p, int f32f, int idx) {
    return f32f ? ((const float*)p)[idx] : bf2f(((const unsigned short*)p)[idx]);
}
__device__ inline bf16x8 load8(const void* p, int f32f, int idx) {
    if (f32f) {
        const float* s = (const float*)p + idx;
        float4 lo = *(const float4*)s;
        float4 hi = *(const float4*)(s + 4);
        bf16x8 t;
        t[0] = (__bf16)lo.x; t[1] = (__bf16)lo.y; t[2] = (__bf16)lo.z; t[3] = (__bf16)lo.w;
        t[4] = (__bf16)hi.x; t[5] = (__bf16)hi.y; t[6] = (__bf16)hi.z; t[7] = (__bf16)hi.w;
        return t;
    }
    FragU t; t.u = *(const uint4*)((const unsigned short*)p + idx);
    return t.b;
}
// mask layout flag: 0 = u8, 1 = i32, 2 = bf16, 3 = f32
__device__ inline int read_mask(const void* p, int flag, int i) {
    if (flag == 1) return ((const int*)p)[i] != 0;
    if (flag == 0) return ((const unsigned char*)p)[i] != 0;
    if (flag == 2) return ((const unsigned short*)p)[i] != 0;
    return ((const float*)p)[i] != 0.0f;
}

__global__ __launch_bounds__(256) void fused_kernel(
    const void* __restrict__ ped,   const void* __restrict__ h_st,
    const void* __restrict__ h_neigh, const void* __restrict__ rela,
    const void* __restrict__ maskp,
    const void* __restrict__ we1_w, const void* __restrict__ we1_b,
    const void* __restrict__ we2_w, const void* __restrict__ we2_b,
    const void* __restrict__ wx1_w, const void* __restrict__ wx1_b,
    const void* __restrict__ wx2_w, const void* __restrict__ wx2_b,
    const void* __restrict__ wa_w,  const void* __restrict__ wa_b,
    const void* __restrict__ wh1_w, const void* __restrict__ wh1_b,
    const void* __restrict__ wh2_w, const void* __restrict__ wh2_b,
    float* __restrict__ out0, float* __restrict__ out1)
{
    __shared__ uint4 wfr[32][64];                             // B-fragments
    __shared__ __align__(16) unsigned short abuf[4][32*72];   // per-wave bounce (stride 72)
    __shared__ __align__(16) unsigned short mi_l[4][NPWV*72]; // per-wave m_i rows, A-layout
    __shared__ float agg_l[NPB][2];
    __shared__ int flagsh[2];

    const int tid  = threadIdx.x;
    const int lane = tid & 63, wv = tid >> 6;
    const int q = lane >> 4, cl = lane & 15;

    // ---- dtype + mask layout detection (wave 0) ----
    if (wv == 0) {
        const unsigned short* hh = (const unsigned short*)h_st;
        bool ok = true;
        #pragma unroll
        for (int t = 0; t < 2; t++) {
            unsigned short v = hh[lane*2 + t];
            if (v) { int e = (v >> 7) & 0xFF; if (e < 90 || e > 165) ok = false; }
        }
        unsigned long long bm = __ballot(ok);
        const unsigned int*   mw = (const unsigned int*)maskp;
        const unsigned short* mh = (const unsigned short*)maskp;
        bool w01 = mw[lane] <= 1u;
        unsigned short h0 = mh[lane*2], h1 = mh[lane*2 + 1];
        bool s16 = (h0 == 0 || h0 == 0x3F80u) && (h1 == 0 || h1 == 0x3F80u);
        bool enz = (h0 != 0);
        unsigned long long bw = __ballot(w01);
        unsigned long long bs = __ballot(s16);
        unsigned long long be = __ballot(enz);
        if (lane == 0) {
            flagsh[1] = (bm == ~0ULL) ? 0 : 1;
            int mf;
            if (bw == ~0ULL) mf = 1;
            else if (bs == ~0ULL) mf = be ? 2 : 3;
            else mf = 0;
            flagsh[0] = mf;
        }
    }
    __syncthreads();
    const int mflag = flagsh[0], f32f = flagsh[1];

    // ---- stage edge-weight B-fragments: we1(16) we2(8) wx1(8) ----
    // frag lane l holds W[k = ks*32 + (l>>4)*8 + j][n = nt*16 + (l&15)]
    for (int idx = tid; idx < 32*64; idx += 256) {
        int f = idx >> 6, l = idx & 63;
        int lq = l >> 4, ln = l & 15;
        const void* W; int nt, ks;
        if (f < 16)      { W = we1_w; ks = f >> 2;        nt = f & 3; }
        else if (f < 24) { int g = f - 16; W = we2_w; ks = g >> 2; nt = g & 3; }
        else             { int g = f - 24; W = wx1_w; ks = g >> 2; nt = g & 3; }
        int k0 = ks*32 + lq*8, n = nt*16 + ln;
        FragU fr;
        #pragma unroll
        for (int j = 0; j < 8; j++)
            fr.s[j] = f32f ? f2bf(((const float*)W)[(k0 + j)*64 + n])
                           : ((const unsigned short*)W)[(k0 + j)*64 + n];
        wfr[f][l] = fr.u;
    }
    __syncthreads();

    float b1v[4], w128v[4], b2v[4], bx1v[4], wx2v0[4], wx2v1[4];
    #pragma unroll
    for (int nt = 0; nt < 4; nt++) {
        int n = nt*16 + cl;
        b1v[nt]   = loadf(we1_b, f32f, n);
        w128v[nt] = loadf(we1_w, f32f, 128*64 + n);  // dist-column weights
        b2v[nt]   = loadf(we2_b, f32f, n);
        bx1v[nt]  = loadf(wx1_b, f32f, n);
        wx2v0[nt] = loadf(wx2_w, f32f, n*2);
        wx2v1[nt] = loadf(wx2_w, f32f, n*2 + 1);
    }
    const float bx20 = loadf(wx2_b, f32f, 0), bx21 = loadf(wx2_b, f32f, 1);
    const f32x4 zz = {0.f, 0.f, 0.f, 0.f};

    // =============== Phase 1: per-node edge MLP ===============
    for (int local = 0; local < NPWV; ++local) {
        const int node = blockIdx.x*NPB + wv*NPWV + local;

        // A fragments (K=128 = [h_i | h_j])
        bf16x8 a_st[2], a_ng[2][2];
        #pragma unroll
        for (int ks = 0; ks < 2; ks++)
            a_st[ks] = load8(h_st, f32f, node*64 + ks*32 + q*8);
        #pragma unroll
        for (int mt = 0; mt < 2; mt++)
            #pragma unroll
            for (int ks = 0; ks < 2; ks++)
                a_ng[mt][ks] = load8(h_neigh, f32f, (node*KK + mt*16 + cl)*64 + ks*32 + q*8);

        // rela / dist / mask (C-layout rows: edge = mt*16 + q*4 + rr)
        float rx[2][4], ry[2][4], dv[2][4]; int mk[2][4];
        #pragma unroll
        for (int mt = 0; mt < 2; mt++)
            #pragma unroll
            for (int rr = 0; rr < 4; rr++) {
                int e = node*KK + mt*16 + q*4 + rr;
                float x = loadf(rela, f32f, e*6), y = loadf(rela, f32f, e*6 + 1);
                rx[mt][rr] = x; ry[mt][rr] = y;
                dv[mt][rr] = sqrtf(x*x + y*y);
                mk[mt][rr] = read_mask(maskp, mflag, e);
            }

        // L1 = silu(E @ we1 + b1) with dist rank-1 fixup
        f32x4 acc[2][4];
        #pragma unroll
        for (int mt = 0; mt < 2; mt++)
            #pragma unroll
            for (int nt = 0; nt < 4; nt++) acc[mt][nt] = zz;
        #pragma unroll
        for (int ks = 0; ks < 4; ks++) {
            bf16x8 a0 = (ks < 2) ? a_st[ks] : a_ng[0][ks - 2];
            bf16x8 a1 = (ks < 2) ? a_st[ks] : a_ng[1][ks - 2];
            #pragma unroll
            for (int nt = 0; nt < 4; nt++) {
                FragU b; b.u = wfr[ks*4 + nt][lane];
                acc[0][nt] = __builtin_amdgcn_mfma_f32_16x16x32_bf16(a0, b.b, acc[0][nt], 0, 0, 0);
                acc[1][nt] = __builtin_amdgcn_mfma_f32_16x16x32_bf16(a1, b.b, acc[1][nt], 0, 0, 0);
            }
        }
        unsigned short* ab = abuf[wv];
        #pragma unroll
        for (int mt = 0; mt < 2; mt++)
            #pragma unroll
            for (int nt = 0; nt < 4; nt++)
                #pragma unroll
                for (int rr = 0; rr < 4; rr++) {
                    float pre = acc[mt][nt][rr] + b1v[nt] + dv[mt][rr]*w128v[nt];
                    ab[(mt*16 + q*4 + rr)*72 + nt*16 + cl] = f2bf(silu_f(pre));
                }
        __syncthreads();   // fence: short-writes -> uint4-reads

        // L2: M = silu(L1 @ we2 + b2)
        f32x4 macc[2][4];
        #pragma unroll
        for (int mt = 0; mt < 2; mt++)
            #pragma unroll
            for (int nt = 0; nt < 4; nt++) macc[mt][nt] = zz;
        #pragma unroll
        for (int ks = 0; ks < 2; ks++) {
            bf16x8 a[2];
            #pragma unroll
            for (int mt = 0; mt < 2; mt++) {
                FragU t; t.u = *(const uint4*)(ab + (mt*16 + cl)*72 + ks*32 + q*8);
                a[mt] = t.b;
            }
            #pragma unroll
            for (int nt = 0; nt < 4; nt++) {
                FragU b; b.u = wfr[16 + ks*4 + nt][lane];
                macc[0][nt] = __builtin_amdgcn_mfma_f32_16x16x32_bf16(a[0], b.b, macc[0][nt], 0, 0, 0);
                macc[1][nt] = __builtin_amdgcn_mfma_f32_16x16x32_bf16(a[1], b.b, macc[1][nt], 0, 0, 0);
            }
        }
        float Mv[2][4][4];
        #pragma unroll
        for (int mt = 0; mt < 2; mt++)
            #pragma unroll
            for (int nt = 0; nt < 4; nt++)
                #pragma unroll
                for (int rr = 0; rr < 4; rr++) Mv[mt][nt][rr] = silu_f(macc[mt][nt][rr] + b2v[nt]);

        // m_i column sums (unmasked) -> mi_l (A-layout row = local)
        #pragma unroll
        for (int nt = 0; nt < 4; nt++) {
            float s = 0.f;
            #pragma unroll
            for (int mt = 0; mt < 2; mt++)
                #pragma unroll
                for (int rr = 0; rr < 4; rr++) s += Mv[mt][nt][rr];
            s += __shfl_xor(s, 16); s += __shfl_xor(s, 32);
            if (q == 0) mi_l[wv][local*72 + nt*16 + cl] = f2bf(s);
        }

        // M -> bounce (fenced by the barrier below before re-read)
        #pragma unroll
        for (int mt = 0; mt < 2; mt++)
            #pragma unroll
            for (int nt = 0; nt < 4; nt++)
                #pragma unroll
                for (int rr = 0; rr < 4; rr++)
                    ab[(mt*16 + q*4 + rr)*72 + nt*16 + cl] = f2bf(Mv[mt][nt][rr]);
        __syncthreads();   // fence: short-writes -> uint4-reads

        // X1 = silu(M @ wx1 + bx1)
        f32x4 xacc[2][4];
        #pragma unroll
        for (int mt = 0; mt < 2; mt++)
            #pragma unroll
            for (int nt = 0; nt < 4; nt++) xacc[mt][nt] = zz;
        #pragma unroll
        for (int ks = 0; ks < 2; ks++) {
            bf16x8 a[2];
            #pragma unroll
            for (int mt = 0; mt < 2; mt++) {
                FragU t; t.u = *(const uint4*)(ab + (mt*16 + cl)*72 + ks*32 + q*8);
                a[mt] = t.b;
            }
            #pragma unroll
            for (int nt = 0; nt < 4; nt++) {
                FragU b; b.u = wfr[24 + ks*4 + nt][lane];
                xacc[0][nt] = __builtin_amdgcn_mfma_f32_16x16x32_bf16(a[0], b.b, xacc[0][nt], 0, 0, 0);
                xacc[1][nt] = __builtin_amdgcn_mfma_f32_16x16x32_bf16(a[1], b.b, xacc[1][nt], 0, 0, 0);
            }
        }

        // FX = silu(X1 @ wx2 + bx2); masked-mean agg
        float ax = 0.f, ay = 0.f, cn = 0.f;
        #pragma unroll
        for (int mt = 0; mt < 2; mt++)
            #pragma unroll
            for (int rr = 0; rr < 4; rr++) {
                float p0 = 0.f, p1 = 0.f;
                #pragma unroll
                for (int nt = 0; nt < 4; nt++) {
                    float xv = silu_f(xacc[mt][nt][rr] + bx1v[nt]);
                    p0 += xv * wx2v0[nt];
                    p1 += xv * wx2v1[nt];
                }
                p0 += __shfl_xor(p0, 1); p0 += __shfl_xor(p0, 2);
                p0 += __shfl_xor(p0, 4); p0 += __shfl_xor(p0, 8);
                p1 += __shfl_xor(p1, 1); p1 += __shfl_xor(p1, 2);
                p1 += __shfl_xor(p1, 4); p1 += __shfl_xor(p1, 8);
                float f0 = silu_f(p0 + bx20), f1 = silu_f(p1 + bx21);
                if (mk[mt][rr]) { ax += rx[mt][rr]*f0; ay += ry[mt][rr]*f1; cn += 1.0f; }
            }
        if (cl != 0) { ax = 0.f; ay = 0.f; cn = 0.f; }
        #pragma unroll
        for (int m = 1; m < 64; m <<= 1) {
            ax += __shfl_xor(ax, m); ay += __shfl_xor(ay, m); cn += __shfl_xor(cn, m);
        }
        if (lane == 0) {
            agg_l[wv*NPWV + local][0] = ax / (cn + 1e-6f);
            agg_l[wv*NPWV + local][1] = ay / (cn + 1e-6f);
        }
        __syncthreads();   // fence loop back-edge
    }

    // =============== Phase 2: node updates ===============
    // re-stage wh1(16) + wh2(8) into wfr[0..23]
    for (int idx = tid; idx < 24*64; idx += 256) {
        int f = idx >> 6, l = idx & 63;
        int lq = l >> 4, ln = l & 15;
        const void* W; int nt, ks;
        if (f < 16) { W = wh1_w; ks = f >> 2; nt = f & 3; }
        else        { int g = f - 16; W = wh2_w; ks = g >> 2; nt = g & 3; }
        int k0 = ks*32 + lq*8, n = nt*16 + ln;
        FragU fr;
        #pragma unroll
        for (int j = 0; j < 8; j++)
            fr.s[j] = f32f ? f2bf(((const float*)W)[(k0 + j)*64 + n])
                           : ((const unsigned short*)W)[(k0 + j)*64 + n];
        wfr[f][l] = fr.u;
    }
    __syncthreads();

    float bh1v[4], bh2v[4];
    #pragma unroll
    for (int nt = 0; nt < 4; nt++) {
        bh1v[nt] = loadf(wh1_b, f32f, nt*16 + cl);
        bh2v[nt] = loadf(wh2_b, f32f, nt*16 + cl);
    }

    const int nb = blockIdx.x*NPB + wv*NPWV;   // 16 nodes per wave, single M-tile

    // A-frags: K=128 = [h_st | m_i]; row m = cl
    bf16x8 afr[4];
    #pragma unroll
    for (int ks = 0; ks < 2; ks++)
        afr[ks] = load8(h_st, f32f, (nb + cl)*64 + ks*32 + q*8);
    #pragma unroll
    for (int ks = 2; ks < 4; ks++) {
        FragU t; t.u = *(const uint4*)(mi_l[wv] + cl*72 + (ks - 2)*32 + q*8);
        afr[ks] = t.b;
    }

    f32x4 acc[4];
    #pragma unroll
    for (int nt = 0; nt < 4; nt++) acc[nt] = zz;
    #pragma unroll
    for (int ks = 0; ks < 4; ks++)
        #pragma unroll
        for (int nt = 0; nt < 4; nt++) {
            FragU b; b.u = wfr[ks*4 + nt][lane];
            acc[nt] = __builtin_amdgcn_mfma_f32_16x16x32_bf16(afr[ks], b.b, acc[nt], 0, 0, 0);
        }
    unsigned short* ab = abuf[wv];
    #pragma unroll
    for (int nt = 0; nt < 4; nt++)
        #pragma unroll
        for (int rr = 0; rr < 4; rr++)
            ab[(q*4 + rr)*72 + nt*16 + cl] = f2bf(silu_f(acc[nt][rr] + bh1v[nt]));
    __syncthreads();   // fence: short-writes -> uint4-reads

    f32x4 c2[4];
    #pragma unroll
    for (int nt = 0; nt < 4; nt++) c2[nt] = zz;
    #pragma unroll
    for (int ks = 0; ks < 2; ks++) {
        FragU t; t.u = *(const uint4*)(ab + cl*72 + ks*32 + q*8);
        bf16x8 a = t.b;
        #pragma unroll
        for (int nt = 0; nt < 4; nt++) {
            FragU b; b.u = wfr[16 + ks*4 + nt][lane];
            c2[nt] = __builtin_amdgcn_mfma_f32_16x16x32_bf16(a, b.b, c2[nt], 0, 0, 0);
        }
    }
    #pragma unroll
    for (int nt = 0; nt < 4; nt++)
        #pragma unroll
        for (int rr = 0; rr < 4; rr++) {
            int row = nb + q*4 + rr, col = nt*16 + cl;
            float hv = loadf(h_st, f32f, row*64 + col);
            out1[row*64 + col] = hv + c2[nt][rr] + bh2v[nt];   // f32 store
        }

    // f_a: x/v/a. lanes 0..31 -> (node = nb + lane/2, j = lane&1)
    if (lane < 32) {
        int m = lane >> 1, j = lane & 1;
        int node = nb + m;
        float s = 0.f;
        for (int h = 0; h < 64; h++)
            s += loadf(h_st, f32f, node*64 + h) * loadf(wa_w, f32f, h*2 + j);
        float a = silu_f(s + loadf(wa_b, f32f, j)) * loadf(ped, f32f, node*6 + 4 + j)
                  + agg_l[wv*NPWV + m][j];
        float v = loadf(ped, f32f, node*6 + 2 + j) + a;
        float x = loadf(ped, f32f, node*6 + j) + v;
        out0[node*6 + j]     = x;   // f32 stores
        out0[node*6 + 2 + j] = v;
        out0[node*6 + 4 + j] = a;
    }
}

extern "C" void kernel_launch(void* const* d_in, const int* in_sizes, int n_in,
                              void* d_out, int out_size, void* d_ws, size_t ws_size,
                              hipStream_t stream) {
    float* out0 = (float*)d_out;
    float* out1 = out0 + (size_t)NODES*6;
    fused_kernel<<<NODES/NPB, 256, 0, stream>>>(
        d_in[0], d_in[1], d_in[2], d_in[3], d_in[4],
        d_in[5], d_in[6], d_in[7], d_in[8],
        d_in[9], d_in[10], d_in[11], d_in[12],
        d_in[13], d_in[14], d_in[15], d_in[16], d_in[17], d_in[18],
        out0, out1);
}

// Round 5
// 332.021 us; speedup vs baseline: 1.3707x; 1.3707x over previous
//
#include <hip/hip_runtime.h>

#define KK 32
#define NODES 16384
#define NPB 16      // nodes per block
#define NPWV 4      // nodes per wave (phase 1)

typedef __bf16 bf16x8 __attribute__((ext_vector_type(8)));
typedef float  f32x4  __attribute__((ext_vector_type(4)));

union FragU { uint4 u; bf16x8 b; unsigned short s[8]; };

__device__ inline float bf2f(unsigned short v) {
    union { unsigned int u; float f; } t; t.u = ((unsigned int)v) << 16; return t.f;
}
__device__ inline unsigned short f2bf(float f) {
    union { float f; unsigned int u; } t; t.f = f;
    unsigned int u = t.u;
    return (unsigned short)((u + 0x7FFFu + ((u >> 16) & 1u)) >> 16);  // RNE
}
__device__ inline unsigned int pkbf(float a, float b) {
    return (unsigned int)f2bf(a) | ((unsigned int)f2bf(b) << 16);
}
__device__ inline float silu_f(float x) { return x / (1.0f + __expf(-x)); }

__device__ inline float loadf(const void* p, int f32f, int idx) {
    return f32f ? ((const float*)p)[idx] : bf2f(((const unsigned short*)p)[idx]);
}
__device__ inline bf16x8 load8(const void* p, int f32f, int idx) {
    if (f32f) {
        const float* s = (const float*)p + idx;
        float4 lo = *(const float4*)s;
        float4 hi = *(const float4*)(s + 4);
        bf16x8 t;
        t[0] = (__bf16)lo.x; t[1] = (__bf16)lo.y; t[2] = (__bf16)lo.z; t[3] = (__bf16)lo.w;
        t[4] = (__bf16)hi.x; t[5] = (__bf16)hi.y; t[6] = (__bf16)hi.z; t[7] = (__bf16)hi.w;
        return t;
    }
    FragU t; t.u = *(const uint4*)((const unsigned short*)p + idx);
    return t.b;
}
// mask layout flag: 0 = u8, 1 = i32, 2 = bf16, 3 = f32
__device__ inline int read_mask(const void* p, int flag, int i) {
    if (flag == 1) return ((const int*)p)[i] != 0;
    if (flag == 0) return ((const unsigned char*)p)[i] != 0;
    if (flag == 2) return ((const unsigned short*)p)[i] != 0;
    return ((const float*)p)[i] != 0.0f;
}
// wave-local compiler fence: LDS ops of one wave execute in issue order in HW;
// this only stops the compiler from reordering across the aliasing accesses.
__device__ inline void fence_lds() {
    __builtin_amdgcn_sched_barrier(0);
    __builtin_amdgcn_wave_barrier();
    __builtin_amdgcn_sched_barrier(0);
}

__global__ __launch_bounds__(256, 2) void fused_kernel(
    const void* __restrict__ ped,   const void* __restrict__ h_st,
    const void* __restrict__ h_neigh, const void* __restrict__ rela,
    const void* __restrict__ maskp,
    const void* __restrict__ we1_w, const void* __restrict__ we1_b,
    const void* __restrict__ we2_w, const void* __restrict__ we2_b,
    const void* __restrict__ wx1_w, const void* __restrict__ wx1_b,
    const void* __restrict__ wx2_w, const void* __restrict__ wx2_b,
    const void* __restrict__ wa_w,  const void* __restrict__ wa_b,
    const void* __restrict__ wh1_w, const void* __restrict__ wh1_b,
    const void* __restrict__ wh2_w, const void* __restrict__ wh2_b,
    float* __restrict__ out0, float* __restrict__ out1)
{
    // weights (K-extended: bias/dist folded into extra K rows)
    __shared__ uint4 wfr[44][64];                                  // 45 KB
    __shared__ __align__(16) unsigned int lbuf[4][2][16][36];      // per-wave bounce, 18.4 KB
    __shared__ __align__(16) unsigned int mibuf[16][36];           // m_i bf16 pairs
    __shared__ __align__(16) unsigned int abuf[16][36];            // phase-2 bounce
    __shared__ float aggbuf[16][2];
    __shared__ int flagsh[2];

    const int tid  = threadIdx.x;
    const int lane = tid & 63, wv = tid >> 6;
    const int q = lane >> 4, cl = lane & 15;

    // ---- dtype + mask layout detection (wave 0) ----
    if (wv == 0) {
        const unsigned short* hh = (const unsigned short*)h_st;
        bool ok = true;
        #pragma unroll
        for (int t = 0; t < 2; t++) {
            unsigned short v = hh[lane*2 + t];
            if (v) { int e = (v >> 7) & 0xFF; if (e < 90 || e > 165) ok = false; }
        }
        unsigned long long bm = __ballot(ok);
        const unsigned int*   mw = (const unsigned int*)maskp;
        const unsigned short* mh = (const unsigned short*)maskp;
        bool w01 = mw[lane] <= 1u;
        unsigned short h0 = mh[lane*2], h1 = mh[lane*2 + 1];
        bool s16 = (h0 == 0 || h0 == 0x3F80u) && (h1 == 0 || h1 == 0x3F80u);
        bool enz = (h0 != 0);
        unsigned long long bw = __ballot(w01);
        unsigned long long bs = __ballot(s16);
        unsigned long long be = __ballot(enz);
        if (lane == 0) {
            flagsh[1] = (bm == ~0ULL) ? 0 : 1;
            int mf;
            if (bw == ~0ULL) mf = 1;
            else if (bs == ~0ULL) mf = be ? 2 : 3;
            else mf = 0;
            flagsh[0] = mf;
        }
    }
    __syncthreads();
    const int mflag = flagsh[0], f32f = flagsh[1];

    // ---- stage phase-1 weights as MFMA fragments (bf16) ----
    // frag (ks,nt), lane l: element j = W_ext[ks*32+(l>>4)*8+j][nt*16+(l&15)]
    // we1_ext: rows 0..128 = we1_w (incl dist row 128), 129 = bias, rest 0
    // we2/wx1_ext: rows 0..63 = W, 64 = bias, rest 0
    for (int idx = tid; idx < 44*64; idx += 256) {
        int f = idx >> 6, l = idx & 63;
        int lq = l >> 4, ln = l & 15;
        const void *W, *B; int g, klim;
        if (f < 20)      { g = f;      W = we1_w; B = we1_b; klim = 129; }
        else if (f < 32) { g = f - 20; W = we2_w; B = we2_b; klim = 64; }
        else             { g = f - 32; W = wx1_w; B = wx1_b; klim = 64; }
        int ks = g >> 2, nt = g & 3;
        int n = nt*16 + ln;
        FragU fr;
        #pragma unroll
        for (int j = 0; j < 8; j++) {
            int k = ks*32 + lq*8 + j;
            float v = (k < klim) ? loadf(W, f32f, k*64 + n)
                                 : (k == klim ? loadf(B, f32f, n) : 0.0f);
            fr.s[j] = f2bf(v);
        }
        wfr[f][l] = fr.u;
    }
    __syncthreads();

    // per-lane constants for the FX dot (wx2 rows for this lane's features)
    float wx2r0[4][4], wx2r1[4][4];
    #pragma unroll
    for (int nt = 0; nt < 4; nt++)
        #pragma unroll
        for (int rr = 0; rr < 4; rr++) {
            int frow = nt*16 + q*4 + rr;
            wx2r0[nt][rr] = loadf(wx2_w, f32f, frow*2);
            wx2r1[nt][rr] = loadf(wx2_w, f32f, frow*2 + 1);
        }
    const float bx20 = loadf(wx2_b, f32f, 0), bx21 = loadf(wx2_b, f32f, 1);
    const f32x4 zz = {0.f, 0.f, 0.f, 0.f};

    // "ones" B/A fragment: k = first element of its K-slice -> 1.0 (bias row)
    FragU bc;
    #pragma unroll
    for (int j = 0; j < 8; j++) bc.s[j] = 0;
    if (q == 0) bc.s[0] = 0x3F80u;

    // =============== Phase 1: per-node edge MLP (transposed chain) ===============
    #pragma unroll 1
    for (int it = 0; it < NPWV; ++it) {
        const int node = blockIdx.x*NPB + wv*NPWV + it;

        // B-operand fragments of E^T: lane holds edge cl, features q*8+j
        bf16x8 bst[2];
        #pragma unroll
        for (int ks = 0; ks < 2; ks++)
            bst[ks] = load8(h_st, f32f, node*64 + ks*32 + q*8);
        bf16x8 bng[2][2];
        #pragma unroll
        for (int et = 0; et < 2; et++)
            #pragma unroll
            for (int ks = 0; ks < 2; ks++)
                bng[et][ks] = load8(h_neigh, f32f, (node*KK + et*16 + cl)*64 + ks*32 + q*8);

        float rx[2], ry[2], dv[2]; int mk[2];
        #pragma unroll
        for (int et = 0; et < 2; et++) {
            int e = node*KK + et*16 + cl;
            rx[et] = loadf(rela, f32f, e*6);
            ry[et] = loadf(rela, f32f, e*6 + 1);
            dv[et] = sqrtf(rx[et]*rx[et] + ry[et]*ry[et]);
            mk[et] = read_mask(maskp, mflag, e);
        }
        FragU bext[2];
        #pragma unroll
        for (int et = 0; et < 2; et++) {
            #pragma unroll
            for (int j = 0; j < 8; j++) bext[et].s[j] = 0;
            if (q == 0) { bext[et].s[0] = f2bf(dv[et]); bext[et].s[1] = 0x3F80u; }
        }

        // GEMM1: L1^T = We1_ext^T @ E_ext^T   (acc row=feature, col=edge)
        f32x4 acc[2][4];
        #pragma unroll
        for (int et = 0; et < 2; et++)
            #pragma unroll
            for (int nt = 0; nt < 4; nt++) acc[et][nt] = zz;
        #pragma unroll
        for (int ks = 0; ks < 5; ks++) {
            bf16x8 b0 = (ks < 2) ? bst[ks] : (ks < 4 ? bng[0][ks-2] : bext[0].b);
            bf16x8 b1 = (ks < 2) ? bst[ks] : (ks < 4 ? bng[1][ks-2] : bext[1].b);
            #pragma unroll
            for (int nt = 0; nt < 4; nt++) {
                FragU w; w.u = wfr[ks*4 + nt][lane];
                acc[0][nt] = __builtin_amdgcn_mfma_f32_16x16x32_bf16(w.b, b0, acc[0][nt], 0, 0, 0);
                acc[1][nt] = __builtin_amdgcn_mfma_f32_16x16x32_bf16(w.b, b1, acc[1][nt], 0, 0, 0);
            }
        }

        // L1 epilogue -> lbuf (bf16 pairs; bias+dist already in K)
        fence_lds();   // prior iteration's lbuf reads precede these writes
        #pragma unroll
        for (int et = 0; et < 2; et++)
            #pragma unroll
            for (int nt = 0; nt < 4; nt++) {
                uint2 pr;
                pr.x = pkbf(silu_f(acc[et][nt][0]), silu_f(acc[et][nt][1]));
                pr.y = pkbf(silu_f(acc[et][nt][2]), silu_f(acc[et][nt][3]));
                *(uint2*)&lbuf[wv][et][cl][nt*8 + q*2] = pr;
            }
        fence_lds();

        // GEMM2: M^T = We2_ext^T @ L1_ext^T
        bf16x8 b2[2][2];
        #pragma unroll
        for (int et = 0; et < 2; et++)
            #pragma unroll
            for (int ks = 0; ks < 2; ks++) {
                FragU t; t.u = *(const uint4*)&lbuf[wv][et][cl][ks*16 + q*4];
                b2[et][ks] = t.b;
            }
        f32x4 mac[2][4];
        #pragma unroll
        for (int et = 0; et < 2; et++)
            #pragma unroll
            for (int nt = 0; nt < 4; nt++) mac[et][nt] = zz;
        #pragma unroll
        for (int ks = 0; ks < 3; ks++) {
            bf16x8 bb0 = (ks < 2) ? b2[0][ks] : bc.b;
            bf16x8 bb1 = (ks < 2) ? b2[1][ks] : bc.b;
            #pragma unroll
            for (int nt = 0; nt < 4; nt++) {
                FragU w; w.u = wfr[20 + ks*4 + nt][lane];
                mac[0][nt] = __builtin_amdgcn_mfma_f32_16x16x32_bf16(w.b, bb0, mac[0][nt], 0, 0, 0);
                mac[1][nt] = __builtin_amdgcn_mfma_f32_16x16x32_bf16(w.b, bb1, mac[1][nt], 0, 0, 0);
            }
        }

        // M epilogue: m_i partials + overwrite lbuf with M
        float mip[4][4];
        fence_lds();   // b2 reads precede the overwrite
        #pragma unroll
        for (int nt = 0; nt < 4; nt++) {
            float v0[2], v1[2], v2[2], v3[2];
            #pragma unroll
            for (int et = 0; et < 2; et++) {
                v0[et] = silu_f(mac[et][nt][0]); v1[et] = silu_f(mac[et][nt][1]);
                v2[et] = silu_f(mac[et][nt][2]); v3[et] = silu_f(mac[et][nt][3]);
                uint2 pr; pr.x = pkbf(v0[et], v1[et]); pr.y = pkbf(v2[et], v3[et]);
                *(uint2*)&lbuf[wv][et][cl][nt*8 + q*2] = pr;
            }
            mip[nt][0] = v0[0] + v0[1]; mip[nt][1] = v1[0] + v1[1];
            mip[nt][2] = v2[0] + v2[1]; mip[nt][3] = v3[0] + v3[1];
        }
        fence_lds();

        // GEMM3: X1^T = Wx1_ext^T @ M_ext^T
        bf16x8 b3[2][2];
        #pragma unroll
        for (int et = 0; et < 2; et++)
            #pragma unroll
            for (int ks = 0; ks < 2; ks++) {
                FragU t; t.u = *(const uint4*)&lbuf[wv][et][cl][ks*16 + q*4];
                b3[et][ks] = t.b;
            }
        f32x4 xac[2][4];
        #pragma unroll
        for (int et = 0; et < 2; et++)
            #pragma unroll
            for (int nt = 0; nt < 4; nt++) xac[et][nt] = zz;
        #pragma unroll
        for (int ks = 0; ks < 3; ks++) {
            bf16x8 bb0 = (ks < 2) ? b3[0][ks] : bc.b;
            bf16x8 bb1 = (ks < 2) ? b3[1][ks] : bc.b;
            #pragma unroll
            for (int nt = 0; nt < 4; nt++) {
                FragU w; w.u = wfr[32 + ks*4 + nt][lane];
                xac[0][nt] = __builtin_amdgcn_mfma_f32_16x16x32_bf16(w.b, bb0, xac[0][nt], 0, 0, 0);
                xac[1][nt] = __builtin_amdgcn_mfma_f32_16x16x32_bf16(w.b, bb1, xac[1][nt], 0, 0, 0);
            }
        }

        // FX: per-edge 2-gate; per-lane partial over this lane's 16 features, reduce over q
        float p0[2] = {0.f, 0.f}, p1[2] = {0.f, 0.f};
        #pragma unroll
        for (int et = 0; et < 2; et++)
            #pragma unroll
            for (int nt = 0; nt < 4; nt++)
                #pragma unroll
                for (int rr = 0; rr < 4; rr++) {
                    float xv = silu_f(xac[et][nt][rr]);
                    p0[et] += xv * wx2r0[nt][rr];
                    p1[et] += xv * wx2r1[nt][rr];
                }
        float axp = 0.f, ayp = 0.f, cnp = 0.f;
        #pragma unroll
        for (int et = 0; et < 2; et++) {
            p0[et] += __shfl_xor(p0[et], 16); p0[et] += __shfl_xor(p0[et], 32);
            p1[et] += __shfl_xor(p1[et], 16); p1[et] += __shfl_xor(p1[et], 32);
            float f0 = silu_f(p0[et] + bx20), f1 = silu_f(p1[et] + bx21);
            if (mk[et]) { axp += rx[et]*f0; ayp += ry[et]*f1; cnp += 1.0f; }
        }
        // reduce agg + m_i over the 16 edge-columns (cl)
        #pragma unroll
        for (int m = 1; m < 16; m <<= 1) {
            axp += __shfl_xor(axp, m); ayp += __shfl_xor(ayp, m); cnp += __shfl_xor(cnp, m);
        }
        #pragma unroll
        for (int nt = 0; nt < 4; nt++)
            #pragma unroll
            for (int rr = 0; rr < 4; rr++) {
                float s = mip[nt][rr];
                s += __shfl_xor(s, 1); s += __shfl_xor(s, 2);
                s += __shfl_xor(s, 4); s += __shfl_xor(s, 8);
                mip[nt][rr] = s;
            }
        const int nl = wv*NPWV + it;
        if (cl == 0) {
            #pragma unroll
            for (int nt = 0; nt < 4; nt++) {
                uint2 pr;
                pr.x = pkbf(mip[nt][0], mip[nt][1]);
                pr.y = pkbf(mip[nt][2], mip[nt][3]);
                *(uint2*)&mibuf[nl][nt*8 + q*2] = pr;
            }
            if (q == 0) {
                aggbuf[nl][0] = axp / (cnp + 1e-6f);
                aggbuf[nl][1] = ayp / (cnp + 1e-6f);
            }
        }
    }

    __syncthreads();

    // =============== Phase 2: node updates (untransposed; waves split nt) ===============
    // restage wh1_ext (20 frags) + wh2_ext (12 frags) into wfr[0..31]
    for (int idx = tid; idx < 32*64; idx += 256) {
        int f = idx >> 6, l = idx & 63;
        int lq = l >> 4, ln = l & 15;
        const void *W, *B; int g, klim;
        if (f < 20) { g = f;      W = wh1_w; B = wh1_b; klim = 128; }
        else        { g = f - 20; W = wh2_w; B = wh2_b; klim = 64; }
        int ks = g >> 2, nt = g & 3;
        int n = nt*16 + ln;
        FragU fr;
        #pragma unroll
        for (int j = 0; j < 8; j++) {
            int k = ks*32 + lq*8 + j;
            float v = (k < klim) ? loadf(W, f32f, k*64 + n)
                                 : (k == klim ? loadf(B, f32f, n) : 0.0f);
            fr.s[j] = f2bf(v);
        }
        wfr[f][l] = fr.u;
    }
    __syncthreads();

    const int nb = blockIdx.x*NPB;

    // A-frags (identical in all waves): K = [h_st(64) | m_i(64) | bias]
    bf16x8 afr[5];
    #pragma unroll
    for (int ks = 0; ks < 2; ks++)
        afr[ks] = load8(h_st, f32f, (nb + cl)*64 + ks*32 + q*8);
    #pragma unroll
    for (int ks = 2; ks < 4; ks++) {
        FragU t; t.u = *(const uint4*)&mibuf[cl][(ks-2)*16 + q*4];
        afr[ks] = t.b;
    }
    afr[4] = bc.b;

    f32x4 hacc = zz;
    #pragma unroll
    for (int ks = 0; ks < 5; ks++) {
        FragU w; w.u = wfr[ks*4 + wv][lane];
        hacc = __builtin_amdgcn_mfma_f32_16x16x32_bf16(afr[ks], w.b, hacc, 0, 0, 0);
    }
    {
        unsigned short* ab = (unsigned short*)abuf;
        #pragma unroll
        for (int rr = 0; rr < 4; rr++)
            ab[(q*4 + rr)*72 + wv*16 + cl] = f2bf(silu_f(hacc[rr]));
    }
    __syncthreads();

    bf16x8 a2[3];
    #pragma unroll
    for (int ks = 0; ks < 2; ks++) {
        FragU t; t.u = *(const uint4*)&abuf[cl][ks*16 + q*4];
        a2[ks] = t.b;
    }
    a2[2] = bc.b;
    f32x4 h2 = zz;
    #pragma unroll
    for (int ks = 0; ks < 3; ks++) {
        FragU w; w.u = wfr[20 + ks*4 + wv][lane];
        h2 = __builtin_amdgcn_mfma_f32_16x16x32_bf16(a2[ks], w.b, h2, 0, 0, 0);
    }
    #pragma unroll
    for (int rr = 0; rr < 4; rr++) {
        int row = nb + q*4 + rr, col = wv*16 + cl;
        out1[row*64 + col] = loadf(h_st, f32f, row*64 + col) + h2[rr];
    }

    // f_a via MFMA (wave 0): s = h_st @ wa_w, cols valid for cl<2
    if (wv == 0) {
        FragU bwa[2];
        #pragma unroll
        for (int ks = 0; ks < 2; ks++) {
            #pragma unroll
            for (int j = 0; j < 8; j++)
                bwa[ks].s[j] = (cl < 2) ? f2bf(loadf(wa_w, f32f, (ks*32 + q*8 + j)*2 + cl)) : 0;
        }
        f32x4 sac = zz;
        #pragma unroll
        for (int ks = 0; ks < 2; ks++)
            sac = __builtin_amdgcn_mfma_f32_16x16x32_bf16(afr[ks], bwa[ks].b, sac, 0, 0, 0);
        if (cl < 2) {
            int j = cl;
            float wb = loadf(wa_b, f32f, j);
            #pragma unroll
            for (int rr = 0; rr < 4; rr++) {
                int row = q*4 + rr, gnode = nb + row;
                float a = silu_f(sac[rr] + wb) * loadf(ped, f32f, gnode*6 + 4 + j)
                          + aggbuf[row][j];
                float v = loadf(ped, f32f, gnode*6 + 2 + j) + a;
                float x = loadf(ped, f32f, gnode*6 + j) + v;
                out0[gnode*6 + j]     = x;
                out0[gnode*6 + 2 + j] = v;
                out0[gnode*6 + 4 + j] = a;
            }
        }
    }
}

extern "C" void kernel_launch(void* const* d_in, const int* in_sizes, int n_in,
                              void* d_out, int out_size, void* d_ws, size_t ws_size,
                              hipStream_t stream) {
    float* out0 = (float*)d_out;
    float* out1 = out0 + (size_t)NODES*6;
    fused_kernel<<<NODES/NPB, 256, 0, stream>>>(
        d_in[0], d_in[1], d_in[2], d_in[3], d_in[4],
        d_in[5], d_in[6], d_in[7], d_in[8],
        d_in[9], d_in[10], d_in[11], d_in[12],
        d_in[13], d_in[14], d_in[15], d_in[16], d_in[17], d_in[18],
        out0, out1);
}